// Round 8
// baseline (20.952 us; speedup 1.0000x reference)
//
#include <hip/hip_runtime.h>
#include <math.h>

#define H    1024
#define NH   16
#define HD   128
#define ID   2048                 // NH*HD
#define NROWS_A (3*ID + ID + NH)  // 6144 qkv + 2048 z + 16 a = 8208
#define NWAVES_A (NROWS_A / 4)    // 2052 waves, 4 rows each
#define MATVEC_BLOCKS (NWAVES_A / 4)  // 513 blocks of 4 waves
#define CONV_FLOATS (3 * ID * 3)      // 18432 floats = 4608 float4
#define CONV_BLOCKS (CONV_FLOATS / 4 / 256)  // 18
#define EPS 1e-6f

__device__ __forceinline__ float waveReduceSumAll(float v) {
#pragma unroll
    for (int off = 1; off < 64; off <<= 1) v += __shfl_xor(v, off, 64);
    return v;
}

// Kernel 1: fused matvec, 4 rows per wave (16 independent float4 loads/lane
// in flight -> 4x the memory-level parallelism of 1-row-per-wave).
// Waves 0..1535 -> qkv rows, 1536..2047 -> z rows, 2048..2051 -> a rows.
// Trailing blocks: conv passthrough + out[] zeroing.
__global__ __launch_bounds__(256) void matvec_qkvza(
    const float* __restrict__ x,
    const float* __restrict__ Wqkv,
    const float* __restrict__ Wz,
    const float* __restrict__ Wa,
    const float* __restrict__ conv,
    float* __restrict__ conv_out,
    float* __restrict__ out,       // zeroed here (K2 atomicAdds into it)
    float* __restrict__ ws_qkv,    // [6144] q|k|v
    float* __restrict__ ws_zsig,   // [2048] z*sigmoid(z)
    float* __restrict__ ws_decay)  // [16] sigmoid(a)
{
    if (blockIdx.x >= MATVEC_BLOCKS) {
        const int cb = blockIdx.x - MATVEC_BLOCKS;
        const int i = cb * 256 + threadIdx.x;
        ((float4*)conv_out)[i] = ((const float4*)conv)[i];
        if (cb == 0) {
            float4 z4 = {0.f, 0.f, 0.f, 0.f};
            ((float4*)out)[threadIdx.x] = z4;
        }
        return;
    }

    const int wave = threadIdx.x >> 6;
    const int lane = threadIdx.x & 63;
    const int w  = blockIdx.x * 4 + wave;   // 0..2051
    const int r0 = w * 4;                   // first of 4 consecutive rows

    const float* base;
    int kind;                               // 0=qkv, 1=z, 2=a (wave-uniform)
    if (r0 < 3 * ID)      { base = Wqkv + (size_t)r0 * H;            kind = 0; }
    else if (r0 < 4 * ID) { base = Wz + (size_t)(r0 - 3 * ID) * H;   kind = 1; }
    else                  { base = Wa + (size_t)(r0 - 4 * ID) * H;   kind = 2; }

    const float4* b4 = (const float4*)base;   // row stride = 256 float4
    const float4* x4 = (const float4*)x;

    float4 xv[4];
#pragma unroll
    for (int i = 0; i < 4; ++i) xv[i] = x4[lane + 64 * i];

    // 16 independent loads (4 rows x 4 chunks), all issued before use
    float4 wr[4][4];
#pragma unroll
    for (int rr = 0; rr < 4; ++rr)
#pragma unroll
        for (int i = 0; i < 4; ++i)
            wr[rr][i] = b4[rr * 256 + lane + 64 * i];

    float acc[4];
#pragma unroll
    for (int rr = 0; rr < 4; ++rr) {
        float a = 0.f;
#pragma unroll
        for (int i = 0; i < 4; ++i)
            a += wr[rr][i].x * xv[i].x + wr[rr][i].y * xv[i].y
               + wr[rr][i].z * xv[i].z + wr[rr][i].w * xv[i].w;
        acc[rr] = a;
    }
    // 4 parallel butterflies (independent chains pipeline through the DS unit)
#pragma unroll
    for (int off = 1; off < 64; off <<= 1) {
#pragma unroll
        for (int rr = 0; rr < 4; ++rr) acc[rr] += __shfl_xor(acc[rr], off, 64);
    }

    if (lane == 0) {
        if (kind == 0) {
            float4 o = {acc[0], acc[1], acc[2], acc[3]};
            *(float4*)(ws_qkv + r0) = o;
        } else if (kind == 1) {
            float4 o;
            o.x = acc[0] / (1.f + expf(-acc[0]));
            o.y = acc[1] / (1.f + expf(-acc[1]));
            o.z = acc[2] / (1.f + expf(-acc[2]));
            o.w = acc[3] / (1.f + expf(-acc[3]));
            *(float4*)(ws_zsig + (r0 - 3 * ID)) = o;
        } else {
            float4 o;
            o.x = 1.f / (1.f + expf(-acc[0]));
            o.y = 1.f / (1.f + expf(-acc[1]));
            o.z = 1.f / (1.f + expf(-acc[2]));
            o.w = 1.f / (1.f + expf(-acc[3]));
            *(float4*)(ws_decay + (r0 - 4 * ID)) = o;
        }
    }
}

// Kernel 2: 256 blocks = (slice s = b>>4, head h = b&15) x 1024 threads.
// b = s*16 + h so all 16 slice-blocks of head h share b%8 -> same XCD L2
// (state of head h fetched ~once per XCD instead of 8x).
// Each block: preload its Wout slice into regs (latency overlapped), read the
// FULL 128x128 state of head h, sn = s*decay + k (outer) v; wave s writes its
// 8 d-rows of new_state; reduce y[e] in-block; RMSNorm + silu-gate; Wout
// partial rows [64s,64s+64) x cols of head h; atomicAdd into out.
__global__ __launch_bounds__(1024) void state_gate_out(
    const float* __restrict__ state_in,
    const float* __restrict__ ws_qkv,
    const float* __restrict__ ws_decay,
    const float* __restrict__ ws_zsig,
    const float* __restrict__ normw,
    const float* __restrict__ Wout,
    float* __restrict__ state_out,
    float* __restrict__ out)
{
    const int s  = blockIdx.x >> 4;
    const int h  = blockIdx.x & 15;
    const int t  = threadIdx.x;
    const int c  = t & 31;     // float4 column (e = 4c..4c+3)
    const int dg = t >> 5;     // 0..31, covers d = 4dg..4dg+3
    const int wv = t >> 6;     // wave, covers d in [8wv, 8wv+8)
    const int lane = t & 63;

    __shared__ float4 part4[16][32];   // 8 KB per-wave y partials
    __shared__ float gated[HD];
    __shared__ float red2[2];

    // ---- Wout register preload (no dependency; overlaps the state chain) ----
    const int rl = t >> 4;            // 0..63
    const int j  = t & 15;
    const int r  = s * 64 + rl;
    const float4* wrow = (const float4*)(Wout + (size_t)r * ID + h * HD);
    const float4 w0 = wrow[j * 2];
    const float4 w1 = wrow[j * 2 + 1];

    const float decay = ws_decay[h];
    const float4 vv = ((const float4*)(ws_qkv + 2 * ID + h * HD))[c];
    const float4 q4 = ((const float4*)(ws_qkv + h * HD))[dg];
    const float4 k4 = ((const float4*)(ws_qkv + ID + h * HD))[dg];

    const float4* sin4 = (const float4*)(state_in  + (size_t)h * HD * HD);
    float4*       sout = (float4*)(state_out + (size_t)h * HD * HD);

    const bool do_write = (wv == s);   // wave-uniform

    float4 acc = {0.f, 0.f, 0.f, 0.f};
    const float qs[4] = {q4.x, q4.y, q4.z, q4.w};
    const float ks[4] = {k4.x, k4.y, k4.z, k4.w};
#pragma unroll
    for (int i = 0; i < 4; ++i) {
        const int d = dg * 4 + i;
        const float4 sv = sin4[d * 32 + c];
        float4 sn;
        sn.x = sv.x * decay + ks[i] * vv.x;
        sn.y = sv.y * decay + ks[i] * vv.y;
        sn.z = sv.z * decay + ks[i] * vv.z;
        sn.w = sv.w * decay + ks[i] * vv.w;
        if (do_write) sout[d * 32 + c] = sn;
        acc.x += qs[i] * sn.x;
        acc.y += qs[i] * sn.y;
        acc.z += qs[i] * sn.z;
        acc.w += qs[i] * sn.w;
    }
    acc.x += __shfl_xor(acc.x, 32, 64);
    acc.y += __shfl_xor(acc.y, 32, 64);
    acc.z += __shfl_xor(acc.z, 32, 64);
    acc.w += __shfl_xor(acc.w, 32, 64);
    if (lane < 32) part4[wv][c] = acc;
    __syncthreads();

    const float* partF = (const float*)part4;
    float y = 0.f;
    if (t < HD) {
#pragma unroll
        for (int w2 = 0; w2 < 16; ++w2) y += partF[w2 * HD + t];
        const float s2 = waveReduceSumAll(y * y);
        if (lane == 0) red2[t >> 6] = s2;
    }
    __syncthreads();
    if (t < HD) {
        const float scale = rsqrtf((red2[0] + red2[1]) * (1.f / HD) + EPS);
        gated[t] = y * scale * normw[t] * ws_zsig[h * HD + t];
    }
    __syncthreads();

    {
        const float4* g4 = (const float4*)gated;
        const float4 g0 = g4[j * 2], g1 = g4[j * 2 + 1];
        float a = w0.x * g0.x + w0.y * g0.y + w0.z * g0.z + w0.w * g0.w
                + w1.x * g1.x + w1.y * g1.y + w1.z * g1.z + w1.w * g1.w;
        a += __shfl_xor(a, 1, 64);
        a += __shfl_xor(a, 2, 64);
        a += __shfl_xor(a, 4, 64);
        a += __shfl_xor(a, 8, 64);
        if (j == 0) atomicAdd(&out[r], a);
    }
}

extern "C" void kernel_launch(void* const* d_in, const int* in_sizes, int n_in,
                              void* d_out, int out_size, void* d_ws, size_t ws_size,
                              hipStream_t stream) {
    const float* x     = (const float*)d_in[0];
    const float* state = (const float*)d_in[1];
    const float* conv  = (const float*)d_in[2];
    const float* Wqkv  = (const float*)d_in[3];
    const float* Wz    = (const float*)d_in[4];
    const float* Wa    = (const float*)d_in[5];
    const float* normw = (const float*)d_in[6];
    const float* Wout  = (const float*)d_in[7];

    float* out       = (float*)d_out;                    // [1024]
    float* new_state = out + H;                          // [16*128*128]
    float* conv_out  = new_state + (size_t)NH * HD * HD; // [18432]

    float* ws       = (float*)d_ws;
    float* ws_qkv   = ws;               // 6144
    float* ws_zsig  = ws + 6144;        // 2048
    float* ws_decay = ws + 8192;        // 16

    matvec_qkvza<<<MATVEC_BLOCKS + CONV_BLOCKS, 256, 0, stream>>>(
        x, Wqkv, Wz, Wa, conv, conv_out, out, ws_qkv, ws_zsig, ws_decay);
    state_gate_out<<<NH * 16, 1024, 0, stream>>>(
        state, ws_qkv, ws_decay, ws_zsig, normw, Wout, new_state, out);
}